// Round 1
// baseline (268.271 us; speedup 1.0000x reference)
//
#include <hip/hip_runtime.h>

// SoftPhongNormalShader, two-phase, FRAGMENT-PARALLEL (R6):
//   Phase 1: per-face table, ONE 16-B row per face (3x 10-bit unorm normals
//            per dword). 1.6 MB -> L2-resident.
//   Phase 2: one THREAD PER FRAGMENT (P*K = 8.4M threads). Each lane does
//            exactly one divergent 16-B gather; the per-pixel softmax blend
//            is an 8-lane __shfl_xor reduction (xor 1/2/4 stays inside the
//            8-lane group; conflict-free swizzle patterns).
//
// Rationale (R6 theory): R1-R5's pixel-parallel form was latency-bound, not
// request-pipe-bound: true TA floor ~1 line/cyc -> ~20 us for our ~11.25
// lines/pixel, vs 88 us measured at only ~13 resident waves/CU (40% occ).
// Fragment-parallel shortens the serial chain to p2f -> 1 gather and raises
// resident waves 8x to fill the per-CU outstanding-miss budget.

typedef float        f4 __attribute__((ext_vector_type(4)));
typedef unsigned int u32;
typedef u32          u4 __attribute__((ext_vector_type(4)));

#define KFRAG 8
#define SIGMA_INV 10000.0f     // 1/1e-4
#define GAMMA_INV 10000.0f     // 1/1e-4
#define ZFAR 100.0f
#define ZRANGE_INV (1.0f / 99.0f)
#define EPSV 1e-10f
#define QSCALE 1023.0f
#define QINV (1.0f / 1023.0f)

__device__ __forceinline__ u32 pack10(float x, float y, float z) {
    // map [-1,1] -> [0,1023] unorm code; code/1023 == (n+1)/2
    u32 qx = (u32)__float2int_rn(__saturatef(x * 0.5f + 0.5f) * QSCALE);
    u32 qy = (u32)__float2int_rn(__saturatef(y * 0.5f + 0.5f) * QSCALE);
    u32 qz = (u32)__float2int_rn(__saturatef(z * 0.5f + 0.5f) * QSCALE);
    return qx | (qy << 10) | (qz << 20);
}

__global__ __launch_bounds__(256) void build_face_tab(
    const float* __restrict__ vn,     // [V,3]
    const int*   __restrict__ faces,  // [F,3]
    u4*          __restrict__ tab,    // [F] 16-B rows
    int F)
{
    int f = blockIdx.x * blockDim.x + threadIdx.x;
    if (f >= F) return;
    int v0 = faces[3*f + 0];
    int v1 = faces[3*f + 1];
    int v2 = faces[3*f + 2];
    u4 row;
    row.x = pack10(vn[3*v0], vn[3*v0+1], vn[3*v0+2]);
    row.y = pack10(vn[3*v1], vn[3*v1+1], vn[3*v1+2]);
    row.z = pack10(vn[3*v2], vn[3*v2+1], vn[3*v2+2]);
    row.w = 0;
    tab[f] = row;
}

__global__ __launch_bounds__(256) void soft_phong_frag(
    const u4*    __restrict__ tab,    // [F] packed face rows
    const float* __restrict__ bary,   // [P,K,3]
    const float* __restrict__ zbuf,   // [P,K]
    const float* __restrict__ dists,  // [P,K]
    const int*   __restrict__ p2f,    // [P,K]
    float*       __restrict__ out,    // [P,4]
    int PK)                           // P * KFRAG
{
    int t = blockIdx.x * blockDim.x + threadIdx.x;   // global fragment id
    if (t >= PK) return;   // PK % 256 == 0 for this problem; never splits a wave

    // ---- loads: start the divergent-gather chain FIRST ----
    int   f   = p2f[t];                              // 4 B coalesced
    u4    row = tab[f >= 0 ? f : 0];                 // ONE divergent 16-B gather
    float z   = zbuf[t];                             // 4 B coalesced
    float d   = dists[t];                            // 4 B coalesced
    const float* bp = bary + (size_t)t * 3;          // 12 B, stride-12 (L1-local)
    float b0 = bp[0], b1 = bp[1], b2 = bp[2];

    bool  m    = (f >= 0);
    float prob = m ? (1.0f / (1.0f + __expf(d * SIGMA_INV))) : 0.0f;
    float zinv = m ? ((ZFAR - z) * ZRANGE_INV) : 0.0f;

    // ---- z_inv_max over the 8 fragments of this pixel (lanes 8k..8k+7) ----
    float zmax = fmaxf(zinv, EPSV);
    zmax = fmaxf(zmax, __shfl_xor(zmax, 1));
    zmax = fmaxf(zmax, __shfl_xor(zmax, 2));
    zmax = fmaxf(zmax, __shfl_xor(zmax, 4));

    // ---- shade: interpolate unorm codes (colors affine in n, sum(b)=1) ----
    u32 w0 = row.x, w1 = row.y, w2 = row.z;
    float sx = b0 * (float)(w0 & 1023u)
             + b1 * (float)(w1 & 1023u)
             + b2 * (float)(w2 & 1023u);
    float sy = b0 * (float)((w0 >> 10) & 1023u)
             + b1 * (float)((w1 >> 10) & 1023u)
             + b2 * (float)((w2 >> 10) & 1023u);
    float sz = b0 * (float)(w0 >> 20)
             + b1 * (float)(w1 >> 20)
             + b2 * (float)(w2 >> 20);
    float cr = sx * QINV;
    float cg = 1.0f - sy * QINV;
    float cb = 1.0f - sz * QINV;

    // ---- per-fragment softmax weight, then 8-lane reductions ----
    float w  = prob * __expf((zinv - zmax) * GAMMA_INV);  // 0 when masked
    float sw = w, swr = w * cr, swg = w * cg, swb = w * cb;
    float tr = 1.0f - prob;                               // transparency factor
    #pragma unroll
    for (int s = 1; s <= 4; s <<= 1) {
        sw  += __shfl_xor(sw,  s);
        swr += __shfl_xor(swr, s);
        swg += __shfl_xor(swg, s);
        swb += __shfl_xor(swb, s);
        tr  *= __shfl_xor(tr,  s);
    }

    // ---- lane k==0 of each 8-group writes the pixel ----
    if ((threadIdx.x & 7) == 0) {
        float delta = fmaxf(__expf((EPSV - zmax) * GAMMA_INV), EPSV);
        float inv   = 1.0f / (sw + delta);
        f4 o = {(swr + delta) * inv,
                (swg + delta) * inv,
                (swb + delta) * inv,
                tr};
        __builtin_nontemporal_store(o, (f4*)out + (t >> 3));
    }
}

extern "C" void kernel_launch(void* const* d_in, const int* in_sizes, int n_in,
                              void* d_out, int out_size, void* d_ws, size_t ws_size,
                              hipStream_t stream) {
    const float* vn    = (const float*)d_in[0];  // verts_normals [V,3]
    const float* bary  = (const float*)d_in[1];  // [N,H,W,K,3]
    const float* zbuf  = (const float*)d_in[2];  // [N,H,W,K]
    const float* dists = (const float*)d_in[3];  // [N,H,W,K]
    const int*   faces = (const int*)d_in[4];    // [F,3]
    const int*   p2f   = (const int*)d_in[5];    // [N,H,W,K]
    float* out = (float*)d_out;                  // [N,H,W,4]

    int PK = in_sizes[2];          // N*H*W*K fragments
    int F  = in_sizes[4] / 3;

    u4* tab = (u4*)d_ws;           // F * 16 B = 1.6 MB
    int block = 256;
    build_face_tab<<<(F + block - 1) / block, block, 0, stream>>>(
        vn, faces, tab, F);
    soft_phong_frag<<<(PK + block - 1) / block, block, 0, stream>>>(
        tab, bary, zbuf, dists, p2f, out, PK);
}